// Round 1
// baseline (428.663 us; speedup 1.0000x reference)
//
#include <hip/hip_runtime.h>

#define NT 256

constexpr int Bg   = 8192;      // graphs
constexpr int NPG  = 40;        // nodes per graph
constexpr int EPG  = 640;       // edges per graph
constexpr int IN_  = 64;
constexpr int HID  = 32;
constexpr int K1   = 20;
constexpr int K2   = 10;
constexpr int OUTC = 10;
constexpr int NE   = Bg * NPG * 16;   // total edges
constexpr int SX   = 68;        // padded X row stride (floats)
constexpr int SH   = 36;        // padded 32-wide row stride (floats)

#define FMA4(acc, a, b) do { \
    acc.x = fmaf((a), (b).x, acc.x); \
    acc.y = fmaf((a), (b).y, acc.y); \
    acc.z = fmaf((a), (b).z, acc.z); \
    acc.w = fmaf((a), (b).w, acc.w); } while (0)

__device__ __forceinline__ float wave_red(float v) {
#pragma unroll
    for (int off = 32; off > 0; off >>= 1) v += __shfl_down(v, off, 64);
    return v;
}

__global__ __launch_bounds__(NT, 2)
void mincut_fused(const float* __restrict__ x, const int* __restrict__ ei,
                  const float* __restrict__ w_c1, const float* __restrict__ b_c1,
                  const float* __restrict__ w_p1, const float* __restrict__ b_p1,
                  const float* __restrict__ w2r_, const float* __restrict__ b2_,
                  const float* __restrict__ w2o_,
                  const float* __restrict__ w_p2, const float* __restrict__ b_p2,
                  const float* __restrict__ w3r_, const float* __restrict__ b3_,
                  const float* __restrict__ w3o_,
                  const float* __restrict__ w_l1, const float* __restrict__ b_l1,
                  const float* __restrict__ w_l2, const float* __restrict__ b_l2,
                  float* __restrict__ out, float* __restrict__ wsg)
{
    __shared__ __align__(16) float sW1[IN_ * HID];   // 2048
    __shared__ __align__(16) float sB1[HID];
    __shared__ __align__(16) float sWp1[HID * K1];   // 640
    __shared__ __align__(16) float sBp1[K1];
    __shared__ __align__(16) float sW2r[HID * HID];
    __shared__ __align__(16) float sB2[HID];
    __shared__ __align__(16) float sW2o[HID * HID];
    __shared__ __align__(16) float sWp2[HID * K2];
    __shared__ __align__(16) float sBp2[K2 + 2];
    __shared__ __align__(16) float sW3r[HID * HID];
    __shared__ __align__(16) float sB3[HID];
    __shared__ __align__(16) float sW3o[HID * HID];
    __shared__ __align__(16) float sXbuf[NPG * SX];  // 2720: X, later S|AS|SS|A3
    __shared__ __align__(16) float sH[NPG * SH];     // 1440
    __shared__ __align__(16) float sXd[NPG * SH];    // 1440
    __shared__ __align__(16) float sA[NPG * NPG];    // 1600
    __shared__ __align__(16) float sA2[K1 * K1];     // 400
    __shared__ __align__(16) float sX2[K1 * SH];     // 720
    __shared__ __align__(16) float sS2[K1 * K2];     // 200
    __shared__ __align__(16) float sX3[K2 * SH];     // 360
    __shared__ __align__(16) float sdinv[NPG];
    __shared__ __align__(16) float srowsA[NPG];
    __shared__ __align__(16) float srowm[NPG];
    __shared__ __align__(16) float spool[HID];
    __shared__ __align__(16) float st1[HID];
    __shared__ __align__(16) float sred[4];
    __shared__ __align__(16) float sc[8];

    float* sS  = sXbuf;          // [40][20] = 800   (alive: phases 5..8)
    float* sAS = sXbuf + 800;    // 800: AS / AX / AS2 / AX3
    float* sSS = sXbuf + 1600;   // 400: SS1 / SS2
    float* sA3 = sXbuf + 2000;   // 100

    const int g    = blockIdx.x;
    const int tid  = threadIdx.x;
    const int lane = tid & 63;
    const int wid  = tid >> 6;

    // ---------------- phase 0: global loads ----------------
    int er0, ec0, er1, ec1, er2 = -1, ec2 = 0;
    {
        const int eb = g * EPG, nb = g * NPG;
        const int* srcp = ei;
        const int* dstp = ei + NE;
        int e = eb + tid;
        er0 = srcp[e] - nb; ec0 = dstp[e] - nb;
        e += NT;
        er1 = srcp[e] - nb; ec1 = dstp[e] - nb;
        if (tid + 2 * NT < EPG) {
            e += NT;
            er2 = srcp[e] - nb; ec2 = dstp[e] - nb;
        }
    }
    for (int i = tid; i < NPG * NPG; i += NT) sA[i] = 0.f;
    {
        const float* xg = x + (size_t)g * (NPG * IN_);
        for (int i = tid; i < NPG * IN_; i += NT) {
            int n = i >> 6, k = i & 63;
            sXbuf[n * SX + k] = xg[i];
        }
    }
    for (int i = tid; i < IN_ * HID; i += NT) sW1[i] = w_c1[i];
    for (int i = tid; i < HID * K1;  i += NT) sWp1[i] = w_p1[i];
    for (int i = tid; i < HID * HID; i += NT) {
        sW2r[i] = w2r_[i]; sW2o[i] = w2o_[i]; sW3r[i] = w3r_[i]; sW3o[i] = w3o_[i];
    }
    for (int i = tid; i < HID * K2; i += NT) sWp2[i] = w_p2[i];
    if (tid < HID) { sB1[tid] = b_c1[tid]; sB2[tid] = b2_[tid]; sB3[tid] = b3_[tid]; }
    else if (tid >= 64 && tid < 64 + K1)  sBp1[tid - 64]  = b_p1[tid - 64];
    else if (tid >= 128 && tid < 128 + K2) sBp2[tid - 128] = b_p2[tid - 128];
    __syncthreads();

    // ---------------- phase 1: adj scatter + H = X @ W1 ----------------
    atomicAdd(&sA[er0 * NPG + ec0], 1.f);
    atomicAdd(&sA[er1 * NPG + ec1], 1.f);
    if (er2 >= 0) atomicAdd(&sA[er2 * NPG + ec2], 1.f);

    for (int o = tid; o < NPG * 8; o += NT) {     // 320 float4 tiles
        int n = o >> 3, fq = o & 7;
        const float4* a4 = (const float4*)(sXbuf + n * SX);
        float4 acc = {0.f, 0.f, 0.f, 0.f};
#pragma unroll
        for (int kk = 0; kk < IN_ / 4; kk++) {
            float4 a = a4[kk];
            const float4* bp = (const float4*)sW1 + (4 * kk) * 8 + fq;
            float4 b0 = bp[0], b1 = bp[8], b2v = bp[16], b3v = bp[24];
            FMA4(acc, a.x, b0); FMA4(acc, a.y, b1);
            FMA4(acc, a.z, b2v); FMA4(acc, a.w, b3v);
        }
        ((float4*)(sH + n * SH))[fq] = acc;
    }
    __syncthreads();

    // ---------------- phase 2: degrees ----------------
    if (tid < NPG) {                 // col sums -> dinv
        float s = 0.f;
#pragma unroll
        for (int r = 0; r < NPG; r++) s += sA[r * NPG + tid];
        sdinv[tid] = rsqrtf(s + 1.f);
    } else if (tid >= 64 && tid < 64 + NPG) {   // row sums (d_flat)
        int n = tid - 64; float s = 0.f;
#pragma unroll
        for (int m = 0; m < NPG; m++) s += sA[n * NPG + m];
        srowsA[n] = s;
    }
    __syncthreads();

    // ---------------- phase 3: H'[r] = dinv[r] * H[r] ----------------
    for (int i = tid; i < NPG * HID; i += NT) {
        int n = i >> 5, f = i & 31;
        sH[n * SH + f] *= sdinv[n];
    }
    __syncthreads();

    // ---------------- phase 4: GCN aggregate -> Xd = relu(...) ----------------
    for (int o = tid; o < NPG * 8; o += NT) {
        int c = o >> 3, fq = o & 7;
        float4 acc = {0.f, 0.f, 0.f, 0.f};
#pragma unroll
        for (int r = 0; r < NPG; r++) {
            float a = sA[r * NPG + c];
            float4 b = ((const float4*)(sH + r * SH))[fq];
            FMA4(acc, a, b);
        }
        float4 hs = ((const float4*)(sH + c * SH))[fq];
        float dc = sdinv[c];
        float4 bb = ((const float4*)sB1)[fq];
        float4 r4;
        r4.x = fmaxf(fmaf(dc, acc.x + hs.x, bb.x), 0.f);
        r4.y = fmaxf(fmaf(dc, acc.y + hs.y, bb.y), 0.f);
        r4.z = fmaxf(fmaf(dc, acc.z + hs.z, bb.z), 0.f);
        r4.w = fmaxf(fmaf(dc, acc.w + hs.w, bb.w), 0.f);
        ((float4*)(sXd + c * SH))[fq] = r4;
    }
    __syncthreads();

    // ---------------- phase 5: S1 logits = Xd @ Wp1 + bp1 ----------------
    for (int o = tid; o < NPG * (K1 / 4); o += NT) {   // 200 tiles
        int n = o / 5, lq = o - n * 5;
        float4 acc = ((const float4*)sBp1)[lq];
#pragma unroll
        for (int k = 0; k < HID; k++) {
            float a = sXd[n * SH + k];
            float4 b = ((const float4*)sWp1)[k * 5 + lq];
            FMA4(acc, a, b);
        }
        ((float4*)(sS + n * K1))[lq] = acc;
    }
    __syncthreads();

    // ---------------- phase 6: row softmax (K1) ----------------
    if (tid < NPG) {
        float* row = sS + tid * K1;
        float v[K1]; float m = -3.0e38f;
#pragma unroll
        for (int k = 0; k < K1; k++) { v[k] = row[k]; m = fmaxf(m, v[k]); }
        float ssum = 0.f;
#pragma unroll
        for (int k = 0; k < K1; k++) { v[k] = __expf(v[k] - m); ssum += v[k]; }
        float inv = 1.f / ssum;
#pragma unroll
        for (int k = 0; k < K1; k++) row[k] = v[k] * inv;
    }
    __syncthreads();

    // ---------------- phase 7: AS = A @ S ; SS = S^T S ----------------
    for (int o = tid; o < 300; o += NT) {
        if (o < 200) {
            int n = o / 5, lq = o - n * 5;
            float4 acc = {0.f, 0.f, 0.f, 0.f};
#pragma unroll
            for (int m = 0; m < NPG; m++) {
                float a = sA[n * NPG + m];
                float4 b = ((const float4*)(sS + m * K1))[lq];
                FMA4(acc, a, b);
            }
            ((float4*)(sAS + n * K1))[lq] = acc;
        } else {
            int oo = o - 200; int k = oo / 5, lq = oo - k * 5;
            float4 acc = {0.f, 0.f, 0.f, 0.f};
#pragma unroll
            for (int n = 0; n < NPG; n++) {
                float a = sS[n * K1 + k];
                float4 b = ((const float4*)(sS + n * K1))[lq];
                FMA4(acc, a, b);
            }
            ((float4*)(sSS + k * K1))[lq] = acc;
        }
    }
    __syncthreads();

    // -------- phase 8: out_adj1 = S^T AS ; X2pool = S^T Xd ; den terms --------
    for (int o = tid; o < 300; o += NT) {
        if (o < 100) {
            int k = o / 5, lq = o - k * 5;
            float4 acc = {0.f, 0.f, 0.f, 0.f};
#pragma unroll
            for (int n = 0; n < NPG; n++) {
                float a = sS[n * K1 + k];
                float4 b = ((const float4*)(sAS + n * K1))[lq];
                FMA4(acc, a, b);
            }
            ((float4*)(sA2 + k * K1))[lq] = acc;
        } else if (o < 260) {
            int oo = o - 100; int k = oo >> 3, fq = oo & 7;
            float4 acc = {0.f, 0.f, 0.f, 0.f};
#pragma unroll
            for (int n = 0; n < NPG; n++) {
                float a = sS[n * K1 + k];
                float4 b = ((const float4*)(sXd + n * SH))[fq];
                FMA4(acc, a, b);
            }
            ((float4*)(sX2 + k * SH))[fq] = acc;
        } else {
            int n = o - 260;
            float s2 = 0.f;
#pragma unroll
            for (int k = 0; k < K1; k++) { float v = sS[n * K1 + k]; s2 = fmaf(v, v, s2); }
            srowm[n] = srowsA[n] * s2;
        }
    }
    __syncthreads();

    // ---------------- phase 9: pool1 scalar reductions ----------------
    if (wid == 0) {
        float v = (lane < K1) ? sA2[lane * K1 + lane] : 0.f;
        v = wave_red(v); if (lane == 0) sc[0] = v;          // num1
    } else if (wid == 1) {
        float v = (lane < NPG) ? srowm[lane] : 0.f;
        v = wave_red(v); if (lane == 0) sc[1] = v;          // den1
    } else if (wid == 2) {
        float v = 0.f;
        for (int i = lane; i < K1 * K1; i += 64) { float t = sSS[i]; v = fmaf(t, t, v); }
        v = wave_red(v); if (lane == 0) sc[2] = v;          // ||SS||_F^2
    }
    __syncthreads();

    // ---------------- phase 10: ortho1 + zero diag; phase 11: row norms ------
    {
        float rn = 1.f / sqrtf(sc[2]);
        const float isk = 0.22360679774997896f;   // 1/sqrt(20)
        float p = 0.f;
        for (int o = tid; o < K1 * K1; o += NT) {
            int k = o / K1, l = o - k * K1;
            float v = sSS[o] * rn - ((k == l) ? isk : 0.f);
            p = fmaf(v, v, p);
        }
        if (tid < K1) sA2[tid * K1 + tid] = 0.f;
        p = wave_red(p);
        if (lane == 0) sred[wid] = p;
    }
    __syncthreads();
    if (tid == 0) sc[3] = sred[0] + sred[1] + sred[2] + sred[3];   // ortho1 sum
    if (tid < K1) {            // own diag already zeroed by this same thread
        float s = 0.f;
#pragma unroll
        for (int l = 0; l < K1; l++) s += sA2[tid * K1 + l];
        srowm[tid] = 1.f / (sqrtf(s) + 1e-15f);
    }
    __syncthreads();

    // ------- phase 12: normalize adj1 + Xw2o = X2pool @ W2o (into sXd) -------
    for (int o = tid; o < 560; o += NT) {
        if (o < 400) {
            int k = o / K1, l = o - k * K1;
            sA2[o] *= srowm[k] * srowm[l];
        } else {
            int oo = o - 400; int k = oo >> 3, fq = oo & 7;
            float4 acc = {0.f, 0.f, 0.f, 0.f};
#pragma unroll
            for (int j = 0; j < HID; j++) {
                float a = sX2[k * SH + j];
                float4 b = ((const float4*)sW2o)[j * 8 + fq];
                FMA4(acc, a, b);
            }
            ((float4*)(sXd + k * SH))[fq] = acc;
        }
    }
    __syncthreads();

    // ---------------- phase 13: AX = adj1 @ X2pool (into sAS) ----------------
    for (int o = tid; o < K1 * 8; o += NT) {
        int k = o >> 3, fq = o & 7;
        float4 acc = {0.f, 0.f, 0.f, 0.f};
#pragma unroll
        for (int l = 0; l < K1; l++) {
            float a = sA2[k * K1 + l];
            float4 b = ((const float4*)(sX2 + l * SH))[fq];
            FMA4(acc, a, b);
        }
        ((float4*)(sAS + k * SH))[fq] = acc;
    }
    __syncthreads();

    // ---------------- phase 14: X2 = relu(AX@W2r + b2 + Xw2o) ----------------
    for (int o = tid; o < K1 * 8; o += NT) {
        int k = o >> 3, fq = o & 7;
        float4 acc = ((const float4*)(sXd + k * SH))[fq];
        float4 bb = ((const float4*)sB2)[fq];
        acc.x += bb.x; acc.y += bb.y; acc.z += bb.z; acc.w += bb.w;
#pragma unroll
        for (int j = 0; j < HID; j++) {
            float a = sAS[k * SH + j];
            float4 b = ((const float4*)sW2r)[j * 8 + fq];
            FMA4(acc, a, b);
        }
        acc.x = fmaxf(acc.x, 0.f); acc.y = fmaxf(acc.y, 0.f);
        acc.z = fmaxf(acc.z, 0.f); acc.w = fmaxf(acc.w, 0.f);
        ((float4*)(sX2 + k * SH))[fq] = acc;
    }
    __syncthreads();

    // ---------------- phase 15: S2 logits + softmax ----------------
    for (int o = tid; o < K1 * K2; o += NT) {
        int n = o / K2, q = o - n * K2;
        float acc = sBp2[q];
#pragma unroll
        for (int j = 0; j < HID; j++) acc = fmaf(sX2[n * SH + j], sWp2[j * K2 + q], acc);
        sS2[o] = acc;
    }
    __syncthreads();
    if (tid < K1) {
        float* row = sS2 + tid * K2;
        float v[K2]; float m = -3.0e38f;
#pragma unroll
        for (int q = 0; q < K2; q++) { v[q] = row[q]; m = fmaxf(m, v[q]); }
        float ssum = 0.f;
#pragma unroll
        for (int q = 0; q < K2; q++) { v[q] = __expf(v[q] - m); ssum += v[q]; }
        float inv = 1.f / ssum;
#pragma unroll
        for (int q = 0; q < K2; q++) row[q] = v[q] * inv;
    }
    __syncthreads();

    // ----- phase 16: AS2 = adj1@S2 ; SS2 ; X3 = S2^T X2 ; den2 terms -----
    for (int o = tid; o < 400; o += NT) {
        if (o < 200) {
            int n = o / K2, l = o - n * K2;
            float acc = 0.f;
#pragma unroll
            for (int m = 0; m < K1; m++) acc = fmaf(sA2[n * K1 + m], sS2[m * K2 + l], acc);
            sAS[n * K2 + l] = acc;
        } else if (o < 300) {
            int oo = o - 200; int k = oo / K2, l = oo - k * K2;
            float acc = 0.f;
#pragma unroll
            for (int n = 0; n < K1; n++) acc = fmaf(sS2[n * K2 + k], sS2[n * K2 + l], acc);
            sSS[k * K2 + l] = acc;
        } else if (o < 380) {
            int oo = o - 300; int k = oo >> 3, fq = oo & 7;
            float4 acc = {0.f, 0.f, 0.f, 0.f};
#pragma unroll
            for (int n = 0; n < K1; n++) {
                float a = sS2[n * K2 + k];
                float4 b = ((const float4*)(sX2 + n * SH))[fq];
                FMA4(acc, a, b);
            }
            ((float4*)(sX3 + k * SH))[fq] = acc;
        } else {
            int n = o - 380;
            float da = 0.f, s2 = 0.f;
#pragma unroll
            for (int l = 0; l < K1; l++) da += sA2[n * K1 + l];
#pragma unroll
            for (int q = 0; q < K2; q++) { float v = sS2[n * K2 + q]; s2 = fmaf(v, v, s2); }
            srowm[n] = da * s2;
        }
    }
    __syncthreads();

    // ---------------- phase 17: out_adj2 = S2^T AS2 ----------------
    for (int o = tid; o < K2 * K2; o += NT) {
        int k = o / K2, l = o - k * K2;
        float acc = 0.f;
#pragma unroll
        for (int n = 0; n < K1; n++) acc = fmaf(sS2[n * K2 + k], sAS[n * K2 + l], acc);
        sA3[o] = acc;
    }
    __syncthreads();

    // ---------------- phase 18: pool2 scalar reductions ----------------
    if (wid == 0) {
        float v = (lane < K2) ? sA3[lane * K2 + lane] : 0.f;
        v = wave_red(v); if (lane == 0) sc[4] = v;          // num2
    } else if (wid == 1) {
        float v = (lane < K1) ? srowm[lane] : 0.f;
        v = wave_red(v); if (lane == 0) sc[5] = v;          // den2
    } else if (wid == 2) {
        float v = 0.f;
        for (int i = lane; i < K2 * K2; i += 64) { float t = sSS[i]; v = fmaf(t, t, v); }
        v = wave_red(v); if (lane == 0) sc[6] = v;          // ||SS2||_F^2
    }
    __syncthreads();

    // -------- phase 19: ortho2 + zero diag + per-graph loss; row norms --------
    {
        float rn = 1.f / sqrtf(sc[6]);
        const float isk = 0.31622776601683794f;   // 1/sqrt(10)
        float p = 0.f;
        for (int o = tid; o < K2 * K2; o += NT) {
            int k = o / K2, l = o - k * K2;
            float v = sSS[o] * rn - ((k == l) ? isk : 0.f);
            p = fmaf(v, v, p);
        }
        if (tid < K2) sA3[tid * K2 + tid] = 0.f;
        p = wave_red(p);
        if (lane == 0) sred[wid] = p;
    }
    __syncthreads();
    if (tid == 0) {
        float o2 = sqrtf(sred[0] + sred[1] + sred[2] + sred[3]);
        float loss = -(sc[0] / sc[1]) + sqrtf(sc[3]) - (sc[4] / sc[5]) + o2;
        wsg[g] = loss;
    }
    if (tid < K2) {
        float s = 0.f;
#pragma unroll
        for (int l = 0; l < K2; l++) s += sA3[tid * K2 + l];
        srowm[tid] = 1.f / (sqrtf(s) + 1e-15f);
    }
    __syncthreads();

    // ------- phase 21: normalize adj2 + Xw3o = X3 @ W3o (into sXd) -------
    for (int o = tid; o < 180; o += NT) {
        if (o < 100) {
            int k = o / K2, l = o - k * K2;
            sA3[o] *= srowm[k] * srowm[l];
        } else {
            int oo = o - 100; int k = oo >> 3, fq = oo & 7;
            float4 acc = {0.f, 0.f, 0.f, 0.f};
#pragma unroll
            for (int j = 0; j < HID; j++) {
                float a = sX3[k * SH + j];
                float4 b = ((const float4*)sW3o)[j * 8 + fq];
                FMA4(acc, a, b);
            }
            ((float4*)(sXd + k * SH))[fq] = acc;
        }
    }
    __syncthreads();

    // ---------------- phase 22: AX3 = adj2 @ X3 (into sAS) ----------------
    for (int o = tid; o < K2 * 8; o += NT) {
        int k = o >> 3, fq = o & 7;
        float4 acc = {0.f, 0.f, 0.f, 0.f};
#pragma unroll
        for (int l = 0; l < K2; l++) {
            float a = sA3[k * K2 + l];
            float4 b = ((const float4*)(sX3 + l * SH))[fq];
            FMA4(acc, a, b);
        }
        ((float4*)(sAS + k * SH))[fq] = acc;
    }
    __syncthreads();

    // ---------------- phase 23: X4 = AX3@W3r + b3 + Xw3o (no relu) ----------
    for (int o = tid; o < K2 * 8; o += NT) {
        int k = o >> 3, fq = o & 7;
        float4 acc = ((const float4*)(sXd + k * SH))[fq];
        float4 bb = ((const float4*)sB3)[fq];
        acc.x += bb.x; acc.y += bb.y; acc.z += bb.z; acc.w += bb.w;
#pragma unroll
        for (int j = 0; j < HID; j++) {
            float a = sAS[k * SH + j];
            float4 b = ((const float4*)sW3r)[j * 8 + fq];
            FMA4(acc, a, b);
        }
        ((float4*)(sX3 + k * SH))[fq] = acc;
    }
    __syncthreads();

    // ---------------- phase 24-26: mean pool + MLP head ----------------
    if (tid < HID) {
        float s = 0.f;
#pragma unroll
        for (int n = 0; n < K2; n++) s += sX3[n * SH + tid];
        spool[tid] = s * (1.f / K2);
    }
    __syncthreads();
    if (tid < HID) {
        float acc = b_l1[tid];
#pragma unroll
        for (int j = 0; j < HID; j++) acc = fmaf(spool[j], w_l1[j * HID + tid], acc);
        st1[tid] = fmaxf(acc, 0.f);
    }
    __syncthreads();
    if (tid < OUTC) {
        float acc = b_l2[tid];
#pragma unroll
        for (int j = 0; j < HID; j++) acc = fmaf(st1[j], w_l2[j * OUTC + tid], acc);
        out[(size_t)g * OUTC + tid] = acc;
    }
}

__global__ void loss_reduce(const float* __restrict__ wsg, float* __restrict__ out)
{
    __shared__ float sred[4];
    int tid = threadIdx.x;
    float s = 0.f;
    for (int i = tid; i < Bg; i += NT) s += wsg[i];
    s = wave_red(s);
    if ((tid & 63) == 0) sred[tid >> 6] = s;
    __syncthreads();
    if (tid == 0) out[(size_t)Bg * OUTC] = (sred[0] + sred[1] + sred[2] + sred[3]) * (1.f / Bg);
}

extern "C" void kernel_launch(void* const* d_in, const int* in_sizes, int n_in,
                              void* d_out, int out_size, void* d_ws, size_t ws_size,
                              hipStream_t stream)
{
    const float* x    = (const float*)d_in[0];
    const int*   ei   = (const int*)  d_in[1];
    // d_in[2] = batch (unused: graphs are contiguous blocks of NPG nodes)
    const float* w_c1 = (const float*)d_in[3];
    const float* b_c1 = (const float*)d_in[4];
    const float* w_p1 = (const float*)d_in[5];
    const float* b_p1 = (const float*)d_in[6];
    const float* w2r  = (const float*)d_in[7];
    const float* b2   = (const float*)d_in[8];
    const float* w2o  = (const float*)d_in[9];
    const float* w_p2 = (const float*)d_in[10];
    const float* b_p2 = (const float*)d_in[11];
    const float* w3r  = (const float*)d_in[12];
    const float* b3   = (const float*)d_in[13];
    const float* w3o  = (const float*)d_in[14];
    const float* w_l1 = (const float*)d_in[15];
    const float* b_l1 = (const float*)d_in[16];
    const float* w_l2 = (const float*)d_in[17];
    const float* b_l2 = (const float*)d_in[18];
    float* out = (float*)d_out;
    float* wsg = (float*)d_ws;

    hipLaunchKernelGGL(mincut_fused, dim3(Bg), dim3(NT), 0, stream,
                       x, ei, w_c1, b_c1, w_p1, b_p1, w2r, b2, w2o,
                       w_p2, b_p2, w3r, b3, w3o, w_l1, b_l1, w_l2, b_l2,
                       out, wsg);
    hipLaunchKernelGGL(loss_reduce, dim3(1), dim3(NT), 0, stream, wsg, out);
}

// Round 3
// 264.283 us; speedup vs baseline: 1.6220x; 1.6220x over previous
//
#include <hip/hip_runtime.h>

#define NT 256

constexpr int Bg   = 8192;      // graphs
constexpr int NPG  = 40;        // nodes per graph
constexpr int EPG  = 640;       // edges per graph
constexpr int IN_  = 64;
constexpr int HID  = 32;
constexpr int K1   = 20;
constexpr int K2   = 10;
constexpr int OUTC = 10;
constexpr int NE   = Bg * NPG * 16;   // total edges
constexpr int SX   = 68;        // padded X row stride (floats)
constexpr int SH   = 36;        // padded 32-wide row stride (floats)

#define FMA4(acc, a, b) do { \
    acc.x = fmaf((a), (b).x, acc.x); \
    acc.y = fmaf((a), (b).y, acc.y); \
    acc.z = fmaf((a), (b).z, acc.z); \
    acc.w = fmaf((a), (b).w, acc.w); } while (0)

__device__ __forceinline__ float wave_red(float v) {
#pragma unroll
    for (int off = 32; off > 0; off >>= 1) v += __shfl_down(v, off, 64);
    return v;
}

__global__ __launch_bounds__(NT, 4)
void mincut_fused(const float* __restrict__ x, const int* __restrict__ ei,
                  const float* __restrict__ w_c1, const float* __restrict__ b_c1,
                  const float* __restrict__ w_p1, const float* __restrict__ b_p1,
                  const float* __restrict__ w2r_, const float* __restrict__ b2_,
                  const float* __restrict__ w2o_,
                  const float* __restrict__ w_p2, const float* __restrict__ b_p2,
                  const float* __restrict__ w3r_, const float* __restrict__ b3_,
                  const float* __restrict__ w3o_,
                  const float* __restrict__ w_l1, const float* __restrict__ b_l1,
                  const float* __restrict__ w_l2, const float* __restrict__ b_l2,
                  float* __restrict__ out, float* __restrict__ wsg)
{
    __shared__ __align__(16) float sXbuf[NPG * SX];  // 2720: X, later S|AS|SS|A3
    __shared__ __align__(16) float sH[NPG * SH];     // raw H = X@W1
    __shared__ __align__(16) float sXd[NPG * SH];
    __shared__ __align__(16) float sA[NPG * NPG];
    __shared__ __align__(16) float sA2[K1 * K1];
    __shared__ __align__(16) float sX2[K1 * SH];
    __shared__ __align__(16) float sS2[K1 * K2];
    __shared__ __align__(16) float sX3[K2 * SH];
    __shared__ __align__(16) float sB1[HID];
    __shared__ __align__(16) float sBp1[K1];
    __shared__ __align__(16) float sB2[HID];
    __shared__ __align__(16) float sBp2[K2 + 2];
    __shared__ __align__(16) float sB3[HID];
    __shared__ __align__(16) float sdinv[NPG];
    __shared__ __align__(16) float srowsA[NPG];
    __shared__ __align__(16) float srowm[NPG];
    __shared__ __align__(16) float spool[HID];
    __shared__ __align__(16) float st1[HID];
    __shared__ __align__(16) float sred[4];
    __shared__ __align__(16) float sc[8];

    float* sS  = sXbuf;          // [40][20] = 800
    float* sAS = sXbuf + 800;    // 800: AS / AX / AS2 / AX3
    float* sSS = sXbuf + 1600;   // 400
    float* sA3 = sXbuf + 2000;   // 100

    const int g    = blockIdx.x;
    const int tid  = threadIdx.x;
    const int lane = tid & 63;
    const int wid  = tid >> 6;

    // ---------------- phase 0: global loads ----------------
    int er0, ec0, er1, ec1, er2 = -1, ec2 = 0;
    {
        const int eb = g * EPG, nb = g * NPG;
        const int* srcp = ei;
        const int* dstp = ei + NE;
        int e = eb + tid;
        er0 = srcp[e] - nb; ec0 = dstp[e] - nb;
        e += NT;
        er1 = srcp[e] - nb; ec1 = dstp[e] - nb;
        if (tid + 2 * NT < EPG) {
            e += NT;
            er2 = srcp[e] - nb; ec2 = dstp[e] - nb;
        }
    }
    for (int i = tid; i < NPG * NPG; i += NT) sA[i] = 0.f;
    {
        const float4* xg = (const float4*)(x + (size_t)g * (NPG * IN_));
        for (int i = tid; i < NPG * (IN_ / 4); i += NT) {   // 640 float4
            int n = i >> 4, k = i & 15;
            ((float4*)(sXbuf + n * SX))[k] = xg[i];
        }
    }
    if (tid < HID) { sB1[tid] = b_c1[tid]; sB2[tid] = b2_[tid]; sB3[tid] = b3_[tid]; }
    else if (tid >= 64 && tid < 64 + K1)   sBp1[tid - 64]  = b_p1[tid - 64];
    else if (tid >= 128 && tid < 128 + K2) sBp2[tid - 128] = b_p2[tid - 128];
    __syncthreads();

    // ---------------- phase 1: adj scatter + H = X @ W1 (2-row tiles) -------
    atomicAdd(&sA[er0 * NPG + ec0], 1.f);
    atomicAdd(&sA[er1 * NPG + ec1], 1.f);
    if (er2 >= 0) atomicAdd(&sA[er2 * NPG + ec2], 1.f);

    if (tid < 160) {                 // 20 row-pairs x 8 col-quads
        int np = tid >> 3, fq = tid & 7;
        int n0 = 2 * np, n1 = n0 + 1;
        const float4* a0p = (const float4*)(sXbuf + n0 * SX);
        const float4* a1p = (const float4*)(sXbuf + n1 * SX);
        const float4* wg  = (const float4*)w_c1;
        float4 acc0 = {0.f,0.f,0.f,0.f}, acc1 = {0.f,0.f,0.f,0.f};
#pragma unroll 4
        for (int kk = 0; kk < IN_ / 4; kk++) {
            float4 a0 = a0p[kk], a1 = a1p[kk];
            float4 w0 = wg[(4*kk+0)*8 + fq];
            float4 w1 = wg[(4*kk+1)*8 + fq];
            float4 w2 = wg[(4*kk+2)*8 + fq];
            float4 w3 = wg[(4*kk+3)*8 + fq];
            FMA4(acc0, a0.x, w0); FMA4(acc0, a0.y, w1);
            FMA4(acc0, a0.z, w2); FMA4(acc0, a0.w, w3);
            FMA4(acc1, a1.x, w0); FMA4(acc1, a1.y, w1);
            FMA4(acc1, a1.z, w2); FMA4(acc1, a1.w, w3);
        }
        ((float4*)(sH + n0 * SH))[fq] = acc0;
        ((float4*)(sH + n1 * SH))[fq] = acc1;
    }
    __syncthreads();

    // ---------------- phase 2: degrees ----------------
    if (tid < NPG) {                 // col sums -> dinv
        float s = 0.f;
#pragma unroll
        for (int r = 0; r < NPG; r++) s += sA[r * NPG + tid];
        sdinv[tid] = rsqrtf(s + 1.f);
    } else if (tid >= 64 && tid < 64 + NPG) {   // row sums (d_flat)
        int n = tid - 64; float s = 0.f;
#pragma unroll
        for (int m = 0; m < NPG; m++) s += sA[n * NPG + m];
        srowsA[n] = s;
    }
    __syncthreads();

    // -------- phase 4: GCN aggregate (dinv folded) -> Xd = relu(...) --------
    if (tid < 160) {
        int cp = tid >> 3, fq = tid & 7;
        int c0 = 2 * cp, c1 = c0 + 1;
        float4 acc0 = {0.f,0.f,0.f,0.f}, acc1 = {0.f,0.f,0.f,0.f};
#pragma unroll 8
        for (int r = 0; r < NPG; r++) {
            float dv = sdinv[r];
            float a0 = sA[r * NPG + c0] * dv;
            float a1 = sA[r * NPG + c1] * dv;
            float4 b = ((const float4*)(sH + r * SH))[fq];
            FMA4(acc0, a0, b);
            FMA4(acc1, a1, b);
        }
        float4 bb = ((const float4*)sB1)[fq];
        float4 h0 = ((const float4*)(sH + c0 * SH))[fq];
        float4 h1 = ((const float4*)(sH + c1 * SH))[fq];
        float d0 = sdinv[c0], d1 = sdinv[c1];
        float4 r0, r1;
        r0.x = fmaxf(fmaf(d0, fmaf(d0, h0.x, acc0.x), bb.x), 0.f);
        r0.y = fmaxf(fmaf(d0, fmaf(d0, h0.y, acc0.y), bb.y), 0.f);
        r0.z = fmaxf(fmaf(d0, fmaf(d0, h0.z, acc0.z), bb.z), 0.f);
        r0.w = fmaxf(fmaf(d0, fmaf(d0, h0.w, acc0.w), bb.w), 0.f);
        r1.x = fmaxf(fmaf(d1, fmaf(d1, h1.x, acc1.x), bb.x), 0.f);
        r1.y = fmaxf(fmaf(d1, fmaf(d1, h1.y, acc1.y), bb.y), 0.f);
        r1.z = fmaxf(fmaf(d1, fmaf(d1, h1.z, acc1.z), bb.z), 0.f);
        r1.w = fmaxf(fmaf(d1, fmaf(d1, h1.w, acc1.w), bb.w), 0.f);
        ((float4*)(sXd + c0 * SH))[fq] = r0;
        ((float4*)(sXd + c1 * SH))[fq] = r1;
    }
    __syncthreads();

    // ---------------- phase 5: S1 logits = Xd @ Wp1 + bp1 ----------------
    if (tid < 100) {                 // 20 row-pairs x 5 l-quads
        int np = tid / 5, lq = tid - np * 5;
        int n0 = 2 * np, n1 = n0 + 1;
        const float4* wg = (const float4*)w_p1;
        float4 bb = ((const float4*)sBp1)[lq];
        float4 acc0 = bb, acc1 = bb;
#pragma unroll 8
        for (int k = 0; k < HID; k++) {
            float a0 = sXd[n0 * SH + k];
            float a1 = sXd[n1 * SH + k];
            float4 w = wg[k * 5 + lq];
            FMA4(acc0, a0, w);
            FMA4(acc1, a1, w);
        }
        ((float4*)(sS + n0 * K1))[lq] = acc0;
        ((float4*)(sS + n1 * K1))[lq] = acc1;
    }
    __syncthreads();

    // ---------------- phase 6: row softmax (K1) ----------------
    if (tid < NPG) {
        float* row = sS + tid * K1;
        float v[K1]; float m = -3.0e38f;
#pragma unroll
        for (int k = 0; k < K1; k++) { v[k] = row[k]; m = fmaxf(m, v[k]); }
        float ssum = 0.f;
#pragma unroll
        for (int k = 0; k < K1; k++) { v[k] = __expf(v[k] - m); ssum += v[k]; }
        float inv = 1.f / ssum;
#pragma unroll
        for (int k = 0; k < K1; k++) row[k] = v[k] * inv;
    }
    __syncthreads();

    // ---------------- phase 7: AS = A @ S ; SS = S^T S ----------------
    if (tid < 150) {
        if (tid < 100) {             // AS: 20 row-pairs x 5 quads
            int np = tid / 5, lq = tid - np * 5;
            int n0 = 2 * np, n1 = n0 + 1;
            float4 acc0 = {0.f,0.f,0.f,0.f}, acc1 = {0.f,0.f,0.f,0.f};
#pragma unroll 8
            for (int m = 0; m < NPG; m++) {
                float a0 = sA[n0 * NPG + m];
                float a1 = sA[n1 * NPG + m];
                float4 b = ((const float4*)(sS + m * K1))[lq];
                FMA4(acc0, a0, b);
                FMA4(acc1, a1, b);
            }
            ((float4*)(sAS + n0 * K1))[lq] = acc0;
            ((float4*)(sAS + n1 * K1))[lq] = acc1;
        } else {                     // SS: 10 k-pairs x 5 quads
            int oo = tid - 100;
            int kp = oo / 5, lq = oo - kp * 5;
            int k0 = 2 * kp, k1 = k0 + 1;
            float4 acc0 = {0.f,0.f,0.f,0.f}, acc1 = {0.f,0.f,0.f,0.f};
#pragma unroll 8
            for (int n = 0; n < NPG; n++) {
                float s0 = sS[n * K1 + k0];
                float s1 = sS[n * K1 + k1];
                float4 b = ((const float4*)(sS + n * K1))[lq];
                FMA4(acc0, s0, b);
                FMA4(acc1, s1, b);
            }
            ((float4*)(sSS + k0 * K1))[lq] = acc0;
            ((float4*)(sSS + k1 * K1))[lq] = acc1;
        }
    }
    __syncthreads();

    // -------- phase 8: out_adj1 = S^T AS ; X2 = S^T Xd ; den terms --------
    if (tid < 170) {
        if (tid < 50) {              // 10 k-pairs x 5 quads
            int kp = tid / 5, lq = tid - kp * 5;
            int k0 = 2 * kp, k1 = k0 + 1;
            float4 acc0 = {0.f,0.f,0.f,0.f}, acc1 = {0.f,0.f,0.f,0.f};
#pragma unroll 8
            for (int n = 0; n < NPG; n++) {
                float s0 = sS[n * K1 + k0];
                float s1 = sS[n * K1 + k1];
                float4 b = ((const float4*)(sAS + n * K1))[lq];
                FMA4(acc0, s0, b);
                FMA4(acc1, s1, b);
            }
            ((float4*)(sA2 + k0 * K1))[lq] = acc0;
            ((float4*)(sA2 + k1 * K1))[lq] = acc1;
        } else if (tid < 130) {      // X2: 10 k-pairs x 8 f-quads
            int oo = tid - 50;
            int kp = oo >> 3, fq = oo & 7;
            int k0 = 2 * kp, k1 = k0 + 1;
            float4 acc0 = {0.f,0.f,0.f,0.f}, acc1 = {0.f,0.f,0.f,0.f};
#pragma unroll 8
            for (int n = 0; n < NPG; n++) {
                float s0 = sS[n * K1 + k0];
                float s1 = sS[n * K1 + k1];
                float4 b = ((const float4*)(sXd + n * SH))[fq];
                FMA4(acc0, s0, b);
                FMA4(acc1, s1, b);
            }
            ((float4*)(sX2 + k0 * SH))[fq] = acc0;
            ((float4*)(sX2 + k1 * SH))[fq] = acc1;
        } else {                     // den terms, n = 0..39
            int n = tid - 130;
            float s2 = 0.f;
#pragma unroll
            for (int k = 0; k < K1; k++) { float v = sS[n * K1 + k]; s2 = fmaf(v, v, s2); }
            srowm[n] = srowsA[n] * s2;
        }
    }
    __syncthreads();

    // ---------------- phase 9: pool1 scalar reductions ----------------
    if (wid == 0) {
        float v = (lane < K1) ? sA2[lane * K1 + lane] : 0.f;
        v = wave_red(v); if (lane == 0) sc[0] = v;          // num1
    } else if (wid == 1) {
        float v = (lane < NPG) ? srowm[lane] : 0.f;
        v = wave_red(v); if (lane == 0) sc[1] = v;          // den1
    } else if (wid == 2) {
        float v = 0.f;
        for (int i = lane; i < K1 * K1; i += 64) { float t = sSS[i]; v = fmaf(t, t, v); }
        v = wave_red(v); if (lane == 0) sc[2] = v;          // ||SS||_F^2
    }
    __syncthreads();

    // ---------------- phase 10: ortho1 + zero diag; row norms ----------------
    {
        float rn = 1.f / sqrtf(sc[2]);
        const float isk = 0.22360679774997896f;   // 1/sqrt(20)
        float p = 0.f;
        for (int o = tid; o < K1 * K1; o += NT) {
            int k = o / K1, l = o - k * K1;
            float v = sSS[o] * rn - ((k == l) ? isk : 0.f);
            p = fmaf(v, v, p);
        }
        if (tid < K1) sA2[tid * K1 + tid] = 0.f;
        p = wave_red(p);
        if (lane == 0) sred[wid] = p;
    }
    __syncthreads();
    if (tid == 0) sc[3] = sred[0] + sred[1] + sred[2] + sred[3];   // ortho1 sum
    if (tid < K1) {
        float s = 0.f;
#pragma unroll
        for (int l = 0; l < K1; l++) s += sA2[tid * K1 + l];
        srowm[tid] = 1.f / (sqrtf(s) + 1e-15f);
    }
    __syncthreads();

    // ------- phase 12: normalize adj1 + Xw2o = X2 @ W2o (into sXd) -------
    for (int o = tid; o < 480; o += NT) {
        if (o < 400) {
            int k = o / K1, l = o - k * K1;
            sA2[o] *= srowm[k] * srowm[l];
        } else {
            int oo = o - 400;        // 10 k-pairs x 8 f-quads
            int kp = oo >> 3, fq = oo & 7;
            int k0 = 2 * kp, k1 = k0 + 1;
            const float4* wg = (const float4*)w2o_;
            float4 acc0 = {0.f,0.f,0.f,0.f}, acc1 = {0.f,0.f,0.f,0.f};
#pragma unroll 4
            for (int j = 0; j < HID; j++) {
                float a0 = sX2[k0 * SH + j];
                float a1 = sX2[k1 * SH + j];
                float4 w = wg[j * 8 + fq];
                FMA4(acc0, a0, w);
                FMA4(acc1, a1, w);
            }
            ((float4*)(sXd + k0 * SH))[fq] = acc0;
            ((float4*)(sXd + k1 * SH))[fq] = acc1;
        }
    }
    __syncthreads();

    // ---------------- phase 13: AX = adj1 @ X2 (into sAS) ----------------
    if (tid < 80) {                  // 10 k-pairs x 8 f-quads
        int kp = tid >> 3, fq = tid & 7;
        int k0 = 2 * kp, k1 = k0 + 1;
        float4 acc0 = {0.f,0.f,0.f,0.f}, acc1 = {0.f,0.f,0.f,0.f};
#pragma unroll
        for (int l = 0; l < K1; l++) {
            float a0 = sA2[k0 * K1 + l];
            float a1 = sA2[k1 * K1 + l];
            float4 b = ((const float4*)(sX2 + l * SH))[fq];
            FMA4(acc0, a0, b);
            FMA4(acc1, a1, b);
        }
        ((float4*)(sAS + k0 * SH))[fq] = acc0;
        ((float4*)(sAS + k1 * SH))[fq] = acc1;
    }
    __syncthreads();

    // ---------------- phase 14: X2 = relu(AX@W2r + b2 + Xw2o) ----------------
    if (tid < 80) {
        int kp = tid >> 3, fq = tid & 7;
        int k0 = 2 * kp, k1 = k0 + 1;
        const float4* wg = (const float4*)w2r_;
        float4 bb = ((const float4*)sB2)[fq];
        float4 acc0 = ((const float4*)(sXd + k0 * SH))[fq];
        float4 acc1 = ((const float4*)(sXd + k1 * SH))[fq];
        acc0.x += bb.x; acc0.y += bb.y; acc0.z += bb.z; acc0.w += bb.w;
        acc1.x += bb.x; acc1.y += bb.y; acc1.z += bb.z; acc1.w += bb.w;
#pragma unroll 4
        for (int j = 0; j < HID; j++) {
            float a0 = sAS[k0 * SH + j];
            float a1 = sAS[k1 * SH + j];
            float4 w = wg[j * 8 + fq];
            FMA4(acc0, a0, w);
            FMA4(acc1, a1, w);
        }
        acc0.x = fmaxf(acc0.x, 0.f); acc0.y = fmaxf(acc0.y, 0.f);
        acc0.z = fmaxf(acc0.z, 0.f); acc0.w = fmaxf(acc0.w, 0.f);
        acc1.x = fmaxf(acc1.x, 0.f); acc1.y = fmaxf(acc1.y, 0.f);
        acc1.z = fmaxf(acc1.z, 0.f); acc1.w = fmaxf(acc1.w, 0.f);
        ((float4*)(sX2 + k0 * SH))[fq] = acc0;
        ((float4*)(sX2 + k1 * SH))[fq] = acc1;
    }
    __syncthreads();

    // ---------------- phase 15: S2 logits + softmax ----------------
    if (tid < K1 * K2) {
        int n = tid / K2, q = tid - n * K2;
        float acc = sBp2[q];
#pragma unroll 8
        for (int j = 0; j < HID; j++) acc = fmaf(sX2[n * SH + j], w_p2[j * K2 + q], acc);
        sS2[tid] = acc;
    }
    __syncthreads();
    if (tid < K1) {
        float* row = sS2 + tid * K2;
        float v[K2]; float m = -3.0e38f;
#pragma unroll
        for (int q = 0; q < K2; q++) { v[q] = row[q]; m = fmaxf(m, v[q]); }
        float ssum = 0.f;
#pragma unroll
        for (int q = 0; q < K2; q++) { v[q] = __expf(v[q] - m); ssum += v[q]; }
        float inv = 1.f / ssum;
#pragma unroll
        for (int q = 0; q < K2; q++) row[q] = v[q] * inv;
    }
    __syncthreads();

    // ----- phase 16: AS2 = adj1@S2 ; SS2 ; X3 = S2^T X2 ; den2 terms -----
    for (int o = tid; o < 400; o += NT) {
        if (o < 200) {
            int n = o / K2, l = o - n * K2;
            float acc = 0.f;
#pragma unroll
            for (int m = 0; m < K1; m++) acc = fmaf(sA2[n * K1 + m], sS2[m * K2 + l], acc);
            sAS[n * K2 + l] = acc;
        } else if (o < 300) {
            int oo = o - 200; int k = oo / K2, l = oo - k * K2;
            float acc = 0.f;
#pragma unroll
            for (int n = 0; n < K1; n++) acc = fmaf(sS2[n * K2 + k], sS2[n * K2 + l], acc);
            sSS[k * K2 + l] = acc;
        } else if (o < 380) {
            int oo = o - 300; int k = oo >> 3, fq = oo & 7;
            float4 acc = {0.f, 0.f, 0.f, 0.f};
#pragma unroll
            for (int n = 0; n < K1; n++) {
                float a = sS2[n * K2 + k];
                float4 b = ((const float4*)(sX2 + n * SH))[fq];
                FMA4(acc, a, b);
            }
            ((float4*)(sX3 + k * SH))[fq] = acc;
        } else {
            int n = o - 380;
            float da = 0.f, s2 = 0.f;
#pragma unroll
            for (int l = 0; l < K1; l++) da += sA2[n * K1 + l];
#pragma unroll
            for (int q = 0; q < K2; q++) { float v = sS2[n * K2 + q]; s2 = fmaf(v, v, s2); }
            srowm[n] = da * s2;
        }
    }
    __syncthreads();

    // ---------------- phase 17: out_adj2 = S2^T AS2 ----------------
    if (tid < K2 * K2) {
        int k = tid / K2, l = tid - k * K2;
        float acc = 0.f;
#pragma unroll
        for (int n = 0; n < K1; n++) acc = fmaf(sS2[n * K2 + k], sAS[n * K2 + l], acc);
        sA3[tid] = acc;
    }
    __syncthreads();

    // ---------------- phase 18: pool2 scalar reductions ----------------
    if (wid == 0) {
        float v = (lane < K2) ? sA3[lane * K2 + lane] : 0.f;
        v = wave_red(v); if (lane == 0) sc[4] = v;          // num2
    } else if (wid == 1) {
        float v = (lane < K1) ? srowm[lane] : 0.f;
        v = wave_red(v); if (lane == 0) sc[5] = v;          // den2
    } else if (wid == 2) {
        float v = 0.f;
        for (int i = lane; i < K2 * K2; i += 64) { float t = sSS[i]; v = fmaf(t, t, v); }
        v = wave_red(v); if (lane == 0) sc[6] = v;          // ||SS2||_F^2
    }
    __syncthreads();

    // -------- phase 19: ortho2 + zero diag + per-graph loss; row norms --------
    {
        float rn = 1.f / sqrtf(sc[6]);
        const float isk = 0.31622776601683794f;   // 1/sqrt(10)
        float p = 0.f;
        if (tid < K2 * K2) {
            int k = tid / K2, l = tid - k * K2;
            float v = sSS[tid] * rn - ((k == l) ? isk : 0.f);
            p = fmaf(v, v, p);
        }
        if (tid < K2) sA3[tid * K2 + tid] = 0.f;
        p = wave_red(p);
        if (lane == 0) sred[wid] = p;
    }
    __syncthreads();
    if (tid == 0) {
        float o2 = sqrtf(sred[0] + sred[1] + sred[2] + sred[3]);
        float loss = -(sc[0] / sc[1]) + sqrtf(sc[3]) - (sc[4] / sc[5]) + o2;
        wsg[g] = loss;
    }
    if (tid < K2) {
        float s = 0.f;
#pragma unroll
        for (int l = 0; l < K2; l++) s += sA3[tid * K2 + l];
        srowm[tid] = 1.f / (sqrtf(s) + 1e-15f);
    }
    __syncthreads();

    // ------- phase 21: normalize adj2 + Xw3o = X3 @ W3o (into sXd) -------
    if (tid < 140) {
        if (tid < 100) {
            int k = tid / K2, l = tid - k * K2;
            sA3[tid] *= srowm[k] * srowm[l];
        } else {
            int oo = tid - 100;      // 5 k-pairs x 8 f-quads
            int kp = oo >> 3, fq = oo & 7;
            int k0 = 2 * kp, k1 = k0 + 1;
            const float4* wg = (const float4*)w3o_;
            float4 acc0 = {0.f,0.f,0.f,0.f}, acc1 = {0.f,0.f,0.f,0.f};
#pragma unroll 4
            for (int j = 0; j < HID; j++) {
                float a0 = sX3[k0 * SH + j];
                float a1 = sX3[k1 * SH + j];
                float4 w = wg[j * 8 + fq];
                FMA4(acc0, a0, w);
                FMA4(acc1, a1, w);
            }
            ((float4*)(sXd + k0 * SH))[fq] = acc0;
            ((float4*)(sXd + k1 * SH))[fq] = acc1;
        }
    }
    __syncthreads();

    // ---------------- phase 22: AX3 = adj2 @ X3 (into sAS) ----------------
    if (tid < 40) {                  // 5 k-pairs x 8 f-quads
        int kp = tid >> 3, fq = tid & 7;
        int k0 = 2 * kp, k1 = k0 + 1;
        float4 acc0 = {0.f,0.f,0.f,0.f}, acc1 = {0.f,0.f,0.f,0.f};
#pragma unroll
        for (int l = 0; l < K2; l++) {
            float a0 = sA3[k0 * K2 + l];
            float a1 = sA3[k1 * K2 + l];
            float4 b = ((const float4*)(sX3 + l * SH))[fq];
            FMA4(acc0, a0, b);
            FMA4(acc1, a1, b);
        }
        ((float4*)(sAS + k0 * SH))[fq] = acc0;
        ((float4*)(sAS + k1 * SH))[fq] = acc1;
    }
    __syncthreads();

    // ---------------- phase 23: X4 = AX3@W3r + b3 + Xw3o (no relu) ----------
    if (tid < 40) {
        int kp = tid >> 3, fq = tid & 7;
        int k0 = 2 * kp, k1 = k0 + 1;
        const float4* wg = (const float4*)w3r_;
        float4 bb = ((const float4*)sB3)[fq];
        float4 acc0 = ((const float4*)(sXd + k0 * SH))[fq];
        float4 acc1 = ((const float4*)(sXd + k1 * SH))[fq];
        acc0.x += bb.x; acc0.y += bb.y; acc0.z += bb.z; acc0.w += bb.w;
        acc1.x += bb.x; acc1.y += bb.y; acc1.z += bb.z; acc1.w += bb.w;
#pragma unroll 4
        for (int j = 0; j < HID; j++) {
            float a0 = sAS[k0 * SH + j];
            float a1 = sAS[k1 * SH + j];
            float4 w = wg[j * 8 + fq];
            FMA4(acc0, a0, w);
            FMA4(acc1, a1, w);
        }
        ((float4*)(sX3 + k0 * SH))[fq] = acc0;
        ((float4*)(sX3 + k1 * SH))[fq] = acc1;
    }
    __syncthreads();

    // ---------------- phase 24-26: mean pool + MLP head ----------------
    if (tid < HID) {
        float s = 0.f;
#pragma unroll
        for (int n = 0; n < K2; n++) s += sX3[n * SH + tid];
        spool[tid] = s * (1.f / K2);
    }
    __syncthreads();
    if (tid < HID) {
        float acc = b_l1[tid];
#pragma unroll 8
        for (int j = 0; j < HID; j++) acc = fmaf(spool[j], w_l1[j * HID + tid], acc);
        st1[tid] = fmaxf(acc, 0.f);
    }
    __syncthreads();
    if (tid < OUTC) {
        float acc = b_l2[tid];
#pragma unroll 8
        for (int j = 0; j < HID; j++) acc = fmaf(st1[j], w_l2[j * OUTC + tid], acc);
        out[(size_t)g * OUTC + tid] = acc;
    }
}

__global__ void loss_reduce(const float* __restrict__ wsg, float* __restrict__ out)
{
    __shared__ float sred[4];
    int tid = threadIdx.x;
    float s = 0.f;
    for (int i = tid; i < Bg; i += NT) s += wsg[i];
    s = wave_red(s);
    if ((tid & 63) == 0) sred[tid >> 6] = s;
    __syncthreads();
    if (tid == 0) out[(size_t)Bg * OUTC] = (sred[0] + sred[1] + sred[2] + sred[3]) * (1.f / Bg);
}

extern "C" void kernel_launch(void* const* d_in, const int* in_sizes, int n_in,
                              void* d_out, int out_size, void* d_ws, size_t ws_size,
                              hipStream_t stream)
{
    const float* x    = (const float*)d_in[0];
    const int*   ei   = (const int*)  d_in[1];
    // d_in[2] = batch (unused: graphs are contiguous blocks of NPG nodes)
    const float* w_c1 = (const float*)d_in[3];
    const float* b_c1 = (const float*)d_in[4];
    const float* w_p1 = (const float*)d_in[5];
    const float* b_p1 = (const float*)d_in[6];
    const float* w2r  = (const float*)d_in[7];
    const float* b2   = (const float*)d_in[8];
    const float* w2o  = (const float*)d_in[9];
    const float* w_p2 = (const float*)d_in[10];
    const float* b_p2 = (const float*)d_in[11];
    const float* w3r  = (const float*)d_in[12];
    const float* b3   = (const float*)d_in[13];
    const float* w3o  = (const float*)d_in[14];
    const float* w_l1 = (const float*)d_in[15];
    const float* b_l1 = (const float*)d_in[16];
    const float* w_l2 = (const float*)d_in[17];
    const float* b_l2 = (const float*)d_in[18];
    float* out = (float*)d_out;
    float* wsg = (float*)d_ws;

    hipLaunchKernelGGL(mincut_fused, dim3(Bg), dim3(NT), 0, stream,
                       x, ei, w_c1, b_c1, w_p1, b_p1, w2r, b2, w2o,
                       w_p2, b_p2, w3r, b3, w3o, w_l1, b_l1, w_l2, b_l2,
                       out, wsg);
    hipLaunchKernelGGL(loss_reduce, dim3(1), dim3(NT), 0, stream, wsg, out);
}